// Round 9
// baseline (161.918 us; speedup 1.0000x reference)
//
#include <hip/hip_runtime.h>

// ContextualAttention: out[b,c,p] = sum_k K[b,k,c] * softmax_k( K[b,:,:] @ F[b,:,p] )
// K = rowwise-normalized (F^T + eps). Flash-style fusion, bf16 MFMA, f32 accum.
// Round 8: 32x32x16 MFMA (2495 vs 2176 TF ubench, half the instructions).
//   Producer wave (kh,qh): 32k x 32q S-tile, 16 chained MFMAs, softmax, P.
//   Consumer wave: 2x2 tiles of 32x32 (64c x 64q), KB frags from L2.
//   Schedule identical to round 7 (KT=64 fat phases, 66 barriers).

#define BATCH 8
#define CH 256
#define NPIX 4096
#define EPSV 1e-7f
#define L2E 1.4426950408889634f

using bf16x8 = __attribute__((ext_vector_type(8))) __bf16;
using bf16x4 = __attribute__((ext_vector_type(4))) __bf16;
using f32x4  = __attribute__((ext_vector_type(4))) float;
using f32x16 = __attribute__((ext_vector_type(16))) float;

__device__ __forceinline__ void gload16(const void* g, void* l) {
  __builtin_amdgcn_global_load_lds(
      (const __attribute__((address_space(1))) unsigned int*)g,
      (__attribute__((address_space(3))) unsigned int*)l, 16, 0, 0);
}

// producer barrier: full drain (its global_load_lds results are read by OTHER
// producer waves next phase; P writes must be visible).
__device__ __forceinline__ void barrier_full() {
  asm volatile("s_waitcnt vmcnt(0) lgkmcnt(0)\n"
               "s_barrier" ::: "memory");
}
// consumer barrier: LDS-only drain; its global->reg prefetch stays in flight.
__device__ __forceinline__ void barrier_lgkm() {
  asm volatile("s_waitcnt lgkmcnt(0)\n"
               "s_barrier" ::: "memory");
}

// ============================================================================
// Prep: per (batch, 32-key tile): inv-norms, normalized bf16 K, two images:
//   KA[b][kt][32 k][256 c]: 16B-unit u stored at u ^ (k&7)  (GEMM1 LDS image)
//   KB[b][kt][256 c][32 k]: plain layout                    (GEMM2 L2 image)
// ============================================================================
__global__ __launch_bounds__(256)
void ca_prep(const float* __restrict__ F, __bf16* __restrict__ KA,
             __bf16* __restrict__ KB) {
  const int b   = blockIdx.x;
  const int kt  = blockIdx.y;          // 128 tiles of 32 keys
  const int kt0 = kt * 32;
  const int t   = threadIdx.x;
  const int k   = t & 31;
  const int h   = (t >> 5) & 1;
  const int w   = t >> 6;

  const float* __restrict__ Fb = F + (size_t)b * CH * NPIX;

  __shared__ float red[4][32];
  __shared__ float invk[32];
  __shared__ __align__(16) __bf16 T[32][264];   // +8 pad

  float fv[32];
  float ss = 0.f;
#pragma unroll
  for (int rep = 0; rep < 32; ++rep) {
    int c = rep * 8 + w * 2 + h;
    float v = Fb[(size_t)c * NPIX + kt0 + k] + EPSV;
    fv[rep] = v;
    ss = fmaf(v, v, ss);
  }
  ss += __shfl_xor(ss, 32, 64);
  if ((t & 32) == 0) red[w][k] = ss;
  __syncthreads();
  if (t < 32) invk[t] = rsqrtf(red[0][t] + red[1][t] + red[2][t] + red[3][t]);
  __syncthreads();
  const float iv = invk[k];
#pragma unroll
  for (int rep = 0; rep < 32; ++rep) {
    int c = rep * 8 + w * 2 + h;
    T[k][c] = (__bf16)(fv[rep] * iv);
  }
  __syncthreads();

  // KA image (swizzled for LDS ds_read)
  __bf16* KAp = KA + ((size_t)b * 128 + kt) * (32 * 256);
#pragma unroll
  for (int pass = 0; pass < 4; ++pass) {
    int kk = pass * 8 + (t >> 5);
    int u  = t & 31;
    bf16x8 v = *(const bf16x8*)&T[kk][u * 8];
    *(bf16x8*)&KAp[kk * 256 + ((u ^ (kk & 7)) * 8)] = v;
  }
  // KB image (plain [c][k] for direct coalesced global frag loads)
  __bf16* KBp = KB + ((size_t)b * 128 + kt) * (256 * 32);
#pragma unroll
  for (int pass = 0; pass < 4; ++pass) {
    int c = pass * 64 + (t >> 2);
    int v = t & 3;
    bf16x8 o;
#pragma unroll
    for (int j = 0; j < 8; ++j) o[j] = T[v * 8 + j][c];
    *(bf16x8*)&KBp[c * 32 + v * 8] = o;
  }
}

// ============================================================================
// Fused attention, producer/consumer, KT=64 fat phases, 32x32x16 MFMA.
// Grid (8 batch, 64 q-tiles), 512 threads = 8 waves. 66 barriers per role.
// smem layout (80KB exact):
//   [0, 64K)  KA dbuf: buf cb at cb*32768, two 16KB sub-tiles (32k x 256c,
//             512B rows, 16B-unit u at u^(k&7))
//   [64K,80K) P dbuf: buf pb at 64K + pb*8192: P[64 q][64 k] bf16, 128B rows
//             of 8 16B-units (8 k each), unit u stored at u^(q&7)
//   lE[2][64] floats aliased at smem+0 (KA buf0 dead in last phase).
// 32x32x16 fragment maps: A row = lane&31, k(c)-elem = (lane>>5)*8+j;
//   B col = lane&31, k-elem = (lane>>5)*8+j;
//   C/D col = lane&31, row = (reg&3) + 8*(reg>>2) + 4*(lane>>5).
// ============================================================================
__global__ __launch_bounds__(512, 4)
void ca_attn8(const float* __restrict__ F, const __bf16* __restrict__ KA,
              const __bf16* __restrict__ KB, float* __restrict__ Out) {
  __shared__ __align__(16) char smem[81920];

  const int tid  = threadIdx.x;
  const int lane = tid & 63;
  const int w    = tid >> 6;            // 0..7
  const int l31  = lane & 31;
  const int hi   = lane >> 5;
  const int b    = blockIdx.x;          // batch fastest -> one batch per XCD
  const int q0   = blockIdx.y * 64;

  const char* KAb = (const char*)(KA + (size_t)b * (size_t)NPIX * CH);
  const char* KBb = (const char*)(KB + (size_t)b * (size_t)NPIX * CH);
  char* PlB = smem + 65536;

  if (w < 4) {
    // =================== producer: GEMM1 + softmax ========================
    const int kh = w >> 1, qh = w & 1;
    const int qcol = q0 + qh * 32 + l31;          // this lane's query pixel
    const float* __restrict__ Fb = F + (size_t)b * CH * NPIX;
    const int wo = w * 8192;            // this wave's 8KB slice of a 32KB tile

    // stage tile 0 -> buf 0 (overlaps Q loads below)
#pragma unroll
    for (int j = 0; j < 8; ++j)
      gload16(KAb + wo + j * 1024 + lane * 16, smem + wo + j * 1024);

    // Q fragments (B operand, pre-scaled by L2E): qf[cs][j] = F[cs*16+hi*8+j][q]
    bf16x8 qf[16];
    float ss = 0.f;
#pragma unroll
    for (int cs = 0; cs < 16; ++cs) {
#pragma unroll
      for (int j = 0; j < 8; ++j) {
        int c = cs * 16 + hi * 8 + j;
        float v = Fb[(size_t)c * NPIX + qcol];
        qf[cs][j] = (__bf16)(v * L2E);
        ss = fmaf(v, v, ss);
      }
    }
    ss += __shfl_xor(ss, 32, 64);       // lane & lane+32 cover complementary c
    // m_q = ||F_q||: provable max of S[:,q] (K rows unit-norm), exact shift.
    const float mq = sqrtf(ss) * L2E;

    float lacc = 0.f;
    const int rowByte = l31 * 512;      // A row within sub-tile
    const int k7 = lane & 7;            // = (k-row)&7 swizzle key
    const int q7 = l31 & 7;             // P-row swizzle key
    const int prow = (qh * 32 + l31) * 128;

    barrier_full();                                  // #1: tile 0 landed

    for (int i = 0; i < 64; ++i) {
      const int cb = i & 1;
      if (i < 63) {                                  // stage tile i+1
        const char* s = KAb + (size_t)(i + 1) * 32768;
        char* d = smem + (cb ^ 1) * 32768;
#pragma unroll
        for (int j = 0; j < 8; ++j)
          gload16(s + wo + j * 1024 + lane * 16, d + wo + j * 1024);
      }

      // GEMM1: S[32k x 32q] = sum_c KA[k][c] * Q[c][q], 16 chained MFMAs
      const char* ab = smem + cb * 32768 + kh * 16384 + rowByte;
      f32x16 acc = (f32x16)0.0f;
      __builtin_amdgcn_s_setprio(1);
#pragma unroll
      for (int cs = 0; cs < 16; ++cs) {
        bf16x8 a = *(const bf16x8*)(ab + ((((cs << 1) | hi) ^ k7) << 4));
        acc = __builtin_amdgcn_mfma_f32_32x32x16_bf16(a, qf[cs], acc, 0, 0, 0);
      }
      __builtin_amdgcn_s_setprio(0);

      // softmax numerators (fixed shift); P rows: k = kh*32 + 8g + 4hi + s
      char* pb = PlB + cb * 8192;
#pragma unroll
      for (int g = 0; g < 4; ++g) {
        bf16x4 pv;
#pragma unroll
        for (int s = 0; s < 4; ++s) {
          float p = __builtin_amdgcn_exp2f(acc[g * 4 + s] - mq);
          lacc += p;
          pv[s] = (__bf16)p;
        }
        *(bf16x4*)(pb + prow + ((((kh << 2) | g) ^ q7) << 4) + hi * 8) = pv;
      }

      barrier_full();                                // #i+2
    }

    // final softmax denominators -> lE (aliased at smem+0; KA buf0 is dead)
    lacc += __shfl_xor(lacc, 32, 64);   // combine hi halves (k-rows)
    float* lE = (float*)smem;
    if (lane < 32) lE[kh * 64 + qh * 32 + l31] = lacc;
    barrier_full();                                  // #66

  } else {
    // =================== consumer: GEMM2 ==================================
    const int cq = w - 4;
    const int c0 = cq * 64;
    const size_t rowByte = (size_t)(c0 + l31) * 64;  // KB row (+ct*2048)
    const int q7 = l31 & 7;
    const int prow = l31 * 128;                      // + qt*32*128

    f32x16 o00 = (f32x16)0.0f, o01 = (f32x16)0.0f;   // o[ct][qt]
    f32x16 o10 = (f32x16)0.0f, o11 = (f32x16)0.0f;

    barrier_lgkm();                                  // #1

    for (int jt = 0; jt < 64; ++jt) {
      // issue KB frag loads for tile jt (full phase to land across barrier)
      // A-frag: row c = c0 + ct*32 + l31, k = kc*16 + hi*8 + j
      const char* t0 = KBb + (size_t)(2 * jt) * 16384 + rowByte + hi * 16;
      const char* t1 = t0 + 16384;
      bf16x8 kb00 = *(const bf16x8*)(t0);            // ct0 kc0
      bf16x8 kb01 = *(const bf16x8*)(t0 + 32);       // ct0 kc1
      bf16x8 kb02 = *(const bf16x8*)(t1);            // ct0 kc2
      bf16x8 kb03 = *(const bf16x8*)(t1 + 32);       // ct0 kc3
      bf16x8 kb10 = *(const bf16x8*)(t0 + 2048);     // ct1 kc0
      bf16x8 kb11 = *(const bf16x8*)(t0 + 2048 + 32);
      bf16x8 kb12 = *(const bf16x8*)(t1 + 2048);
      bf16x8 kb13 = *(const bf16x8*)(t1 + 2048 + 32);

      barrier_lgkm();                                // #jt+2: P(jt) ready

      const char* pb = PlB + (jt & 1) * 8192;
      __builtin_amdgcn_s_setprio(1);
#pragma unroll
      for (int kc = 0; kc < 4; ++kc) {
        const int uo = ((((kc << 1) | hi) ^ q7) << 4);
        bf16x8 pf0 = *(const bf16x8*)(pb + prow + uo);
        bf16x8 pf1 = *(const bf16x8*)(pb + prow + 4096 + uo);
        bf16x8 k0 = kc == 0 ? kb00 : kc == 1 ? kb01 : kc == 2 ? kb02 : kb03;
        bf16x8 k1 = kc == 0 ? kb10 : kc == 1 ? kb11 : kc == 2 ? kb12 : kb13;
        o00 = __builtin_amdgcn_mfma_f32_32x32x16_bf16(k0, pf0, o00, 0, 0, 0);
        o01 = __builtin_amdgcn_mfma_f32_32x32x16_bf16(k0, pf1, o01, 0, 0, 0);
        o10 = __builtin_amdgcn_mfma_f32_32x32x16_bf16(k1, pf0, o10, 0, 0, 0);
        o11 = __builtin_amdgcn_mfma_f32_32x32x16_bf16(k1, pf1, o11, 0, 0, 0);
      }
      __builtin_amdgcn_s_setprio(0);
    }

    barrier_lgkm();                                  // #66: lE published

    // epilogue: normalize and store
    const float* lE = (const float*)smem;
    const float rl0 = 1.0f / (lE[l31] + lE[64 + l31]);
    const float rl1 = 1.0f / (lE[32 + l31] + lE[96 + l31]);
    float* __restrict__ Ob = Out + (size_t)b * CH * NPIX;
#pragma unroll
    for (int r = 0; r < 16; ++r) {
      const int crow = (r & 3) + 8 * (r >> 2) + 4 * hi;
      float* orow0 = Ob + (size_t)(c0 + crow) * NPIX + q0;
      float* orow1 = Ob + (size_t)(c0 + 32 + crow) * NPIX + q0;
      orow0[l31]      = o00[r] * rl0;
      orow0[32 + l31] = o01[r] * rl1;
      orow1[l31]      = o10[r] * rl0;
      orow1[32 + l31] = o11[r] * rl1;
    }
  }
}

// ============================================================================
extern "C" void kernel_launch(void* const* d_in, const int* in_sizes, int n_in,
                              void* d_out, int out_size, void* d_ws, size_t ws_size,
                              hipStream_t stream) {
  const float* F = (const float*)d_in[0];
  float* out = (float*)d_out;
  const size_t imgElems = (size_t)BATCH * NPIX * CH;   // 8.4M bf16 per image

  __bf16* KAi = (__bf16*)d_ws;            // ws >= 33.6 MB (verified rounds 2-7)
  __bf16* KBi = KAi + imgElems;
  ca_prep<<<dim3(BATCH, 128), 256, 0, stream>>>(F, KAi, KBi);
  ca_attn8<<<dim3(BATCH, 64), 512, 0, stream>>>(F, KAi, KBi, out);
}

// Round 10
// 133.106 us; speedup vs baseline: 1.2165x; 1.2165x over previous
//
#include <hip/hip_runtime.h>

// ContextualAttention: out[b,c,p] = sum_k K[b,k,c] * softmax_k( K[b,:,:] @ F[b,:,p] )
// K = rowwise-normalized (F^T + eps). Flash-style fusion, bf16 MFMA, f32 accum.
// Round 9: q=128 per block, 1024 threads, 1 block/CU (grid 8x32): the K stream
//   (KA DMA + KB frags) is fetched ONCE per CU per phase instead of twice
//   (-25% VMEM). Inner structures identical to round 7 (16x16x32, 4x8-deep
//   producer chains, same swizzles); 8 producer + 8 consumer waves.

#define BATCH 8
#define CH 256
#define NPIX 4096
#define EPSV 1e-7f
#define L2E 1.4426950408889634f

using bf16x8 = __attribute__((ext_vector_type(8))) __bf16;
using bf16x4 = __attribute__((ext_vector_type(4))) __bf16;
using f32x4  = __attribute__((ext_vector_type(4))) float;

__device__ __forceinline__ void gload16(const void* g, void* l) {
  __builtin_amdgcn_global_load_lds(
      (const __attribute__((address_space(1))) unsigned int*)g,
      (__attribute__((address_space(3))) unsigned int*)l, 16, 0, 0);
}

// producer barrier: full drain (its global_load_lds results are read by OTHER
// producer waves next phase; P writes must be visible).
__device__ __forceinline__ void barrier_full() {
  asm volatile("s_waitcnt vmcnt(0) lgkmcnt(0)\n"
               "s_barrier" ::: "memory");
}
// consumer barrier: LDS-only drain; its global->reg prefetch stays in flight.
__device__ __forceinline__ void barrier_lgkm() {
  asm volatile("s_waitcnt lgkmcnt(0)\n"
               "s_barrier" ::: "memory");
}

// ============================================================================
// Prep: per (batch, 32-key tile): inv-norms, normalized bf16 K, two images:
//   KA[b][kt][32 k][256 c]: 16B-unit u stored at u ^ (k&7)  (GEMM1 LDS image)
//   KB[b][kt][256 c][32 k]: plain layout                    (GEMM2 L2 image)
// ============================================================================
__global__ __launch_bounds__(256)
void ca_prep(const float* __restrict__ F, __bf16* __restrict__ KA,
             __bf16* __restrict__ KB) {
  const int b   = blockIdx.x;
  const int kt  = blockIdx.y;          // 128 tiles of 32 keys
  const int kt0 = kt * 32;
  const int t   = threadIdx.x;
  const int k   = t & 31;
  const int h   = (t >> 5) & 1;
  const int w   = t >> 6;

  const float* __restrict__ Fb = F + (size_t)b * CH * NPIX;

  __shared__ float red[4][32];
  __shared__ float invk[32];
  __shared__ __align__(16) __bf16 T[32][264];   // +8 pad

  float fv[32];
  float ss = 0.f;
#pragma unroll
  for (int rep = 0; rep < 32; ++rep) {
    int c = rep * 8 + w * 2 + h;
    float v = Fb[(size_t)c * NPIX + kt0 + k] + EPSV;
    fv[rep] = v;
    ss = fmaf(v, v, ss);
  }
  ss += __shfl_xor(ss, 32, 64);
  if ((t & 32) == 0) red[w][k] = ss;
  __syncthreads();
  if (t < 32) invk[t] = rsqrtf(red[0][t] + red[1][t] + red[2][t] + red[3][t]);
  __syncthreads();
  const float iv = invk[k];
#pragma unroll
  for (int rep = 0; rep < 32; ++rep) {
    int c = rep * 8 + w * 2 + h;
    T[k][c] = (__bf16)(fv[rep] * iv);
  }
  __syncthreads();

  // KA image (swizzled for LDS ds_read)
  __bf16* KAp = KA + ((size_t)b * 128 + kt) * (32 * 256);
#pragma unroll
  for (int pass = 0; pass < 4; ++pass) {
    int kk = pass * 8 + (t >> 5);
    int u  = t & 31;
    bf16x8 v = *(const bf16x8*)&T[kk][u * 8];
    *(bf16x8*)&KAp[kk * 256 + ((u ^ (kk & 7)) * 8)] = v;
  }
  // KB image (plain [c][k] for direct coalesced global frag loads)
  __bf16* KBp = KB + ((size_t)b * 128 + kt) * (256 * 32);
#pragma unroll
  for (int pass = 0; pass < 4; ++pass) {
    int c = pass * 64 + (t >> 2);
    int v = t & 3;
    bf16x8 o;
#pragma unroll
    for (int j = 0; j < 8; ++j) o[j] = T[v * 8 + j][c];
    *(bf16x8*)&KBp[c * 32 + v * 8] = o;
  }
}

// ============================================================================
// Fused attention, producer/consumer, q=128/block, KT=64 fat phases.
// Grid (8 batch, 32 q-tiles), 1024 threads = 16 waves, 1 block/CU.
//   waves 0-7  (producer): (kh = w>>2, qh = w&3) -> 32k x 32q GEMM1 + softmax
//   waves 8-15 (consumer): cq = w-8: c0 = (cq>>1)*64, q-half = (cq&1)*64
// smem layout (97.5KB):
//   [0, 64K)   KA dbuf: buf cb at cb*32768, two 16KB sub-tiles (32k x 256c,
//              512B rows, 16B-unit u at u^(k&7))
//   [64K,96K)  P dbuf: buf pb at 64K + pb*16384: P[128 q][64 k] bf16, 128B
//              rows of 8 16B-units (8 k each), unit u stored at u^(q&7)
//   lE[2][128] floats aliased at smem+0 (KA buf0 dead in final phase).
// 66 barriers per role.
// ============================================================================
__global__ __launch_bounds__(1024, 4)
void ca_attn9(const float* __restrict__ F, const __bf16* __restrict__ KA,
              const __bf16* __restrict__ KB, float* __restrict__ Out) {
  __shared__ __align__(16) char smem[98304];

  const int tid  = threadIdx.x;
  const int lane = tid & 63;
  const int w    = tid >> 6;            // 0..15
  const int lq   = lane & 15;
  const int lg   = lane >> 4;
  const int b    = blockIdx.x;          // batch fastest -> one batch per XCD
  const int q0   = blockIdx.y * 128;

  const char* KAb = (const char*)(KA + (size_t)b * (size_t)NPIX * CH);
  const char* KBb = (const char*)(KB + (size_t)b * (size_t)NPIX * CH);
  char* PlB = smem + 65536;

  if (w < 8) {
    // =================== producer: GEMM1 + softmax ========================
    const int kh = w >> 2, qh = w & 3;
    const int qA = q0 + qh * 32 + lq;
    const int qB = qA + 16;
    const float* __restrict__ Fb = F + (size_t)b * CH * NPIX;
    const int wo = w * 4096;            // this wave's 4KB slice of a 32KB tile

    // stage tile 0 -> buf 0 (overlaps Q loads below)
#pragma unroll
    for (int j = 0; j < 4; ++j)
      gload16(KAb + wo + j * 1024 + lane * 16, smem + wo + j * 1024);

    // Q fragments (pre-scaled by L2E) + squared norms for the fixed shift
    bf16x8 qfA[8], qfB[8];
    float ssA = 0.f, ssB = 0.f;
#pragma unroll
    for (int cf = 0; cf < 8; ++cf) {
#pragma unroll
      for (int j = 0; j < 8; ++j) {
        int c = cf * 32 + lg * 8 + j;
        float va = Fb[(size_t)c * NPIX + qA];
        float vb = Fb[(size_t)c * NPIX + qB];
        qfA[cf][j] = (__bf16)(va * L2E);
        qfB[cf][j] = (__bf16)(vb * L2E);
        ssA = fmaf(va, va, ssA);
        ssB = fmaf(vb, vb, ssB);
      }
    }
    ssA += __shfl_xor(ssA, 16, 64); ssA += __shfl_xor(ssA, 32, 64);
    ssB += __shfl_xor(ssB, 16, 64); ssB += __shfl_xor(ssB, 32, 64);
    // m_q = ||F_q||: provable max of S[:,q] (K rows unit-norm), exact shift.
    const float mqA = sqrtf(ssA) * L2E, mqB = sqrtf(ssB) * L2E;

    float lA = 0.f, lB = 0.f;
    const int krow = kh * 16 + lq;      // A row within each 32k sub-tile
    const int ksw  = lq & 7;
    const int rowByte = krow * 512;
    // P write: row q (128B), unit u = ts*4 + kh*2 + (lg>>1), u ^= (q&7)=lq&7,
    // + (lg&1)*8 bytes within unit.
    const int pwRowA = (qh * 32 + lq) * 128;
    const int pwRowB = pwRowA + 16 * 128;
    const int puBase = kh * 2 + (lg >> 1);
    const int pwSub  = ((lg & 1) << 3);
    const int u0 = (puBase ^ ksw) << 4;          // sub-tile 0 unit offset
    const int u1 = ((4 + puBase) ^ ksw) << 4;    // sub-tile 1 unit offset

    barrier_full();                                  // #1: tile 0 landed

    const f32x4 zero = {0.f, 0.f, 0.f, 0.f};
    for (int i = 0; i < 64; ++i) {
      const int cb = i & 1;
      if (i < 63) {                                  // stage tile i+1
        const char* s = KAb + (size_t)(i + 1) * 32768;
        char* d = smem + (cb ^ 1) * 32768;
#pragma unroll
        for (int j = 0; j < 4; ++j)
          gload16(s + wo + j * 1024 + lane * 16, d + wo + j * 1024);
      }

      // GEMM1: 4 independent 8-deep chains (2 sub-tiles x 2 q-frags)
      const char* ab0 = smem + cb * 32768 + rowByte;          // sub-tile 0
      const char* ab1 = ab0 + 16384;                          // sub-tile 1
      f32x4 s00 = zero, s01 = zero, s10 = zero, s11 = zero;
      __builtin_amdgcn_s_setprio(1);
#pragma unroll
      for (int cf = 0; cf < 8; ++cf) {
        const int uo = ((((cf << 2) | lg) ^ ksw) << 4);
        bf16x8 a0 = *(const bf16x8*)(ab0 + uo);
        bf16x8 a1 = *(const bf16x8*)(ab1 + uo);
        s00 = __builtin_amdgcn_mfma_f32_16x16x32_bf16(a0, qfA[cf], s00, 0, 0, 0);
        s01 = __builtin_amdgcn_mfma_f32_16x16x32_bf16(a0, qfB[cf], s01, 0, 0, 0);
        s10 = __builtin_amdgcn_mfma_f32_16x16x32_bf16(a1, qfA[cf], s10, 0, 0, 0);
        s11 = __builtin_amdgcn_mfma_f32_16x16x32_bf16(a1, qfB[cf], s11, 0, 0, 0);
      }
      __builtin_amdgcn_s_setprio(0);

      // softmax numerators (fixed shift), write P
      char* pb = PlB + cb * 16384;
      bf16x4 pv00, pv01, pv10, pv11;
#pragma unroll
      for (int r = 0; r < 4; ++r) {
        float p00 = __builtin_amdgcn_exp2f(s00[r] - mqA);
        float p01 = __builtin_amdgcn_exp2f(s01[r] - mqB);
        float p10 = __builtin_amdgcn_exp2f(s10[r] - mqA);
        float p11 = __builtin_amdgcn_exp2f(s11[r] - mqB);
        lA += p00 + p10; lB += p01 + p11;
        pv00[r] = (__bf16)p00; pv01[r] = (__bf16)p01;
        pv10[r] = (__bf16)p10; pv11[r] = (__bf16)p11;
      }
      *(bf16x4*)(pb + pwRowA + u0 + pwSub) = pv00;
      *(bf16x4*)(pb + pwRowB + u0 + pwSub) = pv01;
      *(bf16x4*)(pb + pwRowA + u1 + pwSub) = pv10;
      *(bf16x4*)(pb + pwRowB + u1 + pwSub) = pv11;

      barrier_full();                                // #i+2
    }

    // final softmax denominators -> lE (aliased at smem+0; KA buf0 is dead)
    lA += __shfl_xor(lA, 16, 64); lA += __shfl_xor(lA, 32, 64);
    lB += __shfl_xor(lB, 16, 64); lB += __shfl_xor(lB, 32, 64);
    float* lE = (float*)smem;
    if (lg == 0) lE[kh * 128 + qh * 32 + lq] = lA;
    if (lg == 1) lE[kh * 128 + qh * 32 + 16 + lq] = lB;
    barrier_full();                                  // #66

  } else {
    // =================== consumer: GEMM2 ==================================
    const int cq  = w - 8;
    const int c0  = (cq >> 1) * 64;
    const int qh2 = cq & 1;                          // q-half (64 q)
    const size_t fragBase = (size_t)(c0 + lq) * 64 + (size_t)lg * 16;
    // pf read: row = qh2*64 + qf*16 + lq, unit u = kf*4+lg, u ^= (lq&7)
    const int prRow = (qh2 * 64 + lq) * 128;
    const int prU0  = ((0 * 4 + lg) ^ (lq & 7)) << 4;   // kf=0
    const int prU1  = ((1 * 4 + lg) ^ (lq & 7)) << 4;   // kf=1

    const f32x4 zero = {0.f, 0.f, 0.f, 0.f};
    f32x4 oacc[4][4];
#pragma unroll
    for (int i = 0; i < 4; ++i)
#pragma unroll
      for (int j = 0; j < 4; ++j) oacc[i][j] = zero;

    barrier_lgkm();                                  // #1

    for (int jt = 0; jt < 64; ++jt) {
      // issue KB frag loads for tile jt (full phase to land across barrier)
      const char* kb0 = KBb + (size_t)(2 * jt) * 16384 + fragBase;
      const char* kb1 = kb0 + 16384;
      bf16x8 k00 = *(const bf16x8*)(kb0);
      bf16x8 k01 = *(const bf16x8*)(kb0 + 1024);
      bf16x8 k02 = *(const bf16x8*)(kb0 + 2048);
      bf16x8 k03 = *(const bf16x8*)(kb0 + 3072);
      bf16x8 k10 = *(const bf16x8*)(kb1);
      bf16x8 k11 = *(const bf16x8*)(kb1 + 1024);
      bf16x8 k12 = *(const bf16x8*)(kb1 + 2048);
      bf16x8 k13 = *(const bf16x8*)(kb1 + 3072);

      barrier_lgkm();                                // #jt+2: P(jt) ready

      const char* pb = PlB + (jt & 1) * 16384;
      __builtin_amdgcn_s_setprio(1);
#pragma unroll
      for (int qf = 0; qf < 4; ++qf) {
        bf16x8 pf0 = *(const bf16x8*)(pb + prRow + qf * 2048 + prU0);
        oacc[0][qf] = __builtin_amdgcn_mfma_f32_16x16x32_bf16(k00, pf0, oacc[0][qf], 0, 0, 0);
        oacc[1][qf] = __builtin_amdgcn_mfma_f32_16x16x32_bf16(k01, pf0, oacc[1][qf], 0, 0, 0);
        oacc[2][qf] = __builtin_amdgcn_mfma_f32_16x16x32_bf16(k02, pf0, oacc[2][qf], 0, 0, 0);
        oacc[3][qf] = __builtin_amdgcn_mfma_f32_16x16x32_bf16(k03, pf0, oacc[3][qf], 0, 0, 0);
      }
#pragma unroll
      for (int qf = 0; qf < 4; ++qf) {
        bf16x8 pf1 = *(const bf16x8*)(pb + prRow + qf * 2048 + prU1);
        oacc[0][qf] = __builtin_amdgcn_mfma_f32_16x16x32_bf16(k10, pf1, oacc[0][qf], 0, 0, 0);
        oacc[1][qf] = __builtin_amdgcn_mfma_f32_16x16x32_bf16(k11, pf1, oacc[1][qf], 0, 0, 0);
        oacc[2][qf] = __builtin_amdgcn_mfma_f32_16x16x32_bf16(k12, pf1, oacc[2][qf], 0, 0, 0);
        oacc[3][qf] = __builtin_amdgcn_mfma_f32_16x16x32_bf16(k13, pf1, oacc[3][qf], 0, 0, 0);
      }
      __builtin_amdgcn_s_setprio(0);
    }

    barrier_lgkm();                                  // #66: lE published

    // epilogue: normalize and store
    const float* lE = (const float*)smem;
    const int qb = qh2 * 64;
    float rl0 = 1.0f / (lE[qb + 0 * 16 + lq] + lE[128 + qb + 0 * 16 + lq]);
    float rl1 = 1.0f / (lE[qb + 1 * 16 + lq] + lE[128 + qb + 1 * 16 + lq]);
    float rl2 = 1.0f / (lE[qb + 2 * 16 + lq] + lE[128 + qb + 2 * 16 + lq]);
    float rl3 = 1.0f / (lE[qb + 3 * 16 + lq] + lE[128 + qb + 3 * 16 + lq]);
    float* __restrict__ Ob = Out + (size_t)b * CH * NPIX;
#pragma unroll
    for (int ct = 0; ct < 4; ++ct) {
#pragma unroll
      for (int r = 0; r < 4; ++r) {
        const int c = c0 + ct * 16 + lg * 4 + r;
        float* orow = Ob + (size_t)c * NPIX + q0 + qb;
        orow[0 * 16 + lq] = oacc[ct][0][r] * rl0;
        orow[1 * 16 + lq] = oacc[ct][1][r] * rl1;
        orow[2 * 16 + lq] = oacc[ct][2][r] * rl2;
        orow[3 * 16 + lq] = oacc[ct][3][r] * rl3;
      }
    }
  }
}

// ============================================================================
extern "C" void kernel_launch(void* const* d_in, const int* in_sizes, int n_in,
                              void* d_out, int out_size, void* d_ws, size_t ws_size,
                              hipStream_t stream) {
  const float* F = (const float*)d_in[0];
  float* out = (float*)d_out;
  const size_t imgElems = (size_t)BATCH * NPIX * CH;   // 8.4M bf16 per image

  __bf16* KAi = (__bf16*)d_ws;            // ws >= 33.6 MB (verified rounds 2-8)
  __bf16* KBi = KAi + imgElems;
  ca_prep<<<dim3(BATCH, 128), 256, 0, stream>>>(F, KAi, KBi);
  ca_attn9<<<dim3(BATCH, 32), 1024, 0, stream>>>(F, KAi, KBi, out);
}